// Round 8
// baseline (624.402 us; speedup 1.0000x reference)
//
#include <hip/hip_runtime.h>
#include <math.h>

// ---------------------------------------------------------------------------
// Net_37512244363273: 5-level edge-conditioned graph conv + voxel pooling + FC
// Round 8: round 7's scatter/hist cost ~= N_elements x ~57B fabric per
// device-scope atomic (82 MB for 1.43M ops). Seg 0 (1M edges, 75% of all
// elements) now uses a two-level LDS radix CSR build with ZERO per-element
// global atomics: part0 (8-bucket partition, LDS counts + 8 global
// atomics/block, records (ea,x[src]) packed), hist0/scatter0 (64 blocks =
// bucket x bin-slice, histogram + cursors in LDS, bins exclusively owned),
// conv0 (thread-per-node streaming contiguous float4 records). Segs 1-9 stay
// on the round-7 bucketed-atomic path. Falls back to the full round-7 path
// if ws_size < ~50 MB.
// Output: [8,10] log_softmax (80) + closs = 81 floats.
// ---------------------------------------------------------------------------

#define NBUCK 8
#define C0CAP 133120            // seg0 per-bucket capacity: 1M/8 + 2048 (>6 sigma)

// ---- segment descriptor for CSR builds ----
struct SegArgs {
    const int* idx[10];
    int*       cnt[10];
    int*       rp [10];
    int*       out[10];
    int        n  [10];
    int        nb [10];
    int        shift[10];
    int        tstart[11];
};

struct ScanAux {
    int* tilesum;
    int* tileoff;
    int  sstart[11];
    int  T;
};

// XCD-bucketed histogram (per-element global atomics; used for small segs).
__global__ __launch_bounds__(256) void hist_all_k(SegArgs a) {
    int B = blockIdx.x;
    int bucket = B % NBUCK;
    int T = B / NBUCK;
    int s = 0;
    while (s < 9 && T >= a.tstart[s + 1]) s++;
    int i = (T - a.tstart[s]) * 256 + threadIdx.x;
    if (i >= a.n[s]) return;
    int d = a.idx[s][i];
    if ((d >> a.shift[s]) != bucket) return;
    atomicAdd(&a.cnt[s][d], 1);
}

// 3-phase hierarchical scan over all 10 segments' cnt arrays.
__global__ __launch_bounds__(256) void scanA_k(SegArgs a, ScanAux x) {
    int b = blockIdx.x;
    int s = 0;
    while (s < 9 && b >= x.sstart[s + 1]) s++;
    int tloc = b - x.sstart[s];
    int nb = a.nb[s];
    const int* cnt = a.cnt[s];
    int i0 = tloc * 4096 + threadIdx.x * 16;
    int sum = 0;
    #pragma unroll
    for (int k = 0; k < 16; k++) {
        int i = i0 + k;
        if (i < nb) sum += cnt[i];
    }
    #pragma unroll
    for (int o = 32; o; o >>= 1) sum += __shfl_down(sum, o);
    __shared__ int red[4];
    if ((threadIdx.x & 63) == 0) red[threadIdx.x >> 6] = sum;
    __syncthreads();
    if (threadIdx.x == 0)
        x.tilesum[b] = red[0] + red[1] + red[2] + red[3];
}

__global__ __launch_bounds__(64) void scanB_k(SegArgs a, ScanAux x) {
    int lane = threadIdx.x;
    int orig = (lane < x.T) ? x.tilesum[lane] : 0;
    int val = orig;
    #pragma unroll
    for (int d = 1; d < 64; d <<= 1) {
        int v = __shfl_up(val, d);
        if (lane >= d) val += v;
    }
    int excl = val - orig;
    int s = 0;
    while (s < 9 && lane >= x.sstart[s + 1]) s++;
    int segExcl = __shfl(excl, x.sstart[s]);
    if (lane < x.T) {
        x.tileoff[lane] = excl - segExcl;
        if (lane == x.sstart[s + 1] - 1)
            a.rp[s][a.nb[s]] = val - segExcl;
    }
}

__global__ __launch_bounds__(256) void scanC_k(SegArgs a, ScanAux x) {
    int b = blockIdx.x;
    int s = 0;
    while (s < 9 && b >= x.sstart[s + 1]) s++;
    int tloc = b - x.sstart[s];
    int nb = a.nb[s];
    const int* cnt = a.cnt[s];
    int* rp = a.rp[s];
    int i0 = tloc * 4096 + threadIdx.x * 16;
    int v[16];
    int sum = 0;
    #pragma unroll
    for (int k = 0; k < 16; k++) {
        int i = i0 + k;
        v[k] = (i < nb) ? cnt[i] : 0;
        sum += v[k];
    }
    __shared__ int sc[256];
    int acc = sum;
    sc[threadIdx.x] = acc;
    __syncthreads();
    for (int d = 1; d < 256; d <<= 1) {
        int t2 = (threadIdx.x >= d) ? sc[threadIdx.x - d] : 0;
        __syncthreads();
        acc += t2;
        sc[threadIdx.x] = acc;
        __syncthreads();
    }
    int running = x.tileoff[b] + (acc - sum);
    #pragma unroll
    for (int k = 0; k < 16; k++) {
        int i = i0 + k;
        if (i < nb) rp[i] = running;
        running += v[k];
    }
}

// XCD-bucketed countdown-scatter (per-element global atomics; small segs).
__global__ __launch_bounds__(256) void scatter_all_k(SegArgs a) {
    int B = blockIdx.x;
    int bucket = B % NBUCK;
    int T = B / NBUCK;
    int s = 0;
    while (s < 9 && T >= a.tstart[s + 1]) s++;
    int i = (T - a.tstart[s]) * 256 + threadIdx.x;
    if (i >= a.n[s]) return;
    int d = a.idx[s][i];
    if ((d >> a.shift[s]) != bucket) return;
    int p = atomicSub(&a.cnt[s][d], 1) - 1;
    a.out[s][a.rp[s][d] + p] = i;
}

// ---------------------------------------------------------------------------
// Seg-0 LDS radix pipeline (no per-element global atomics).
// ---------------------------------------------------------------------------
// part0: partition 1M edges into 8 dst-buckets; record = (ea0,ea1,ea2,x[src]).
__global__ __launch_bounds__(256) void part0_k(
    const int* __restrict__ src, const int* __restrict__ dst,
    const float* __restrict__ ea, const float* __restrict__ x0,
    int* __restrict__ keys, float4* __restrict__ pay,
    int* __restrict__ bktcnt, int E)
{
    __shared__ int lcnt[8], lbase[8], lcur[8];
    int t = threadIdx.x;
    int i = blockIdx.x * 256 + t;
    if (t < 8) lcnt[t] = 0;
    __syncthreads();
    int d = 0, b = 0;
    float4 r = make_float4(0.f, 0.f, 0.f, 0.f);
    bool val = i < E;
    if (val) {
        d = dst[i];
        b = d >> 13;                       // 64K bins / 8 buckets
        r.x = ea[i * 3]; r.y = ea[i * 3 + 1]; r.z = ea[i * 3 + 2];
        r.w = x0[src[i]];
        atomicAdd(&lcnt[b], 1);            // LDS
    }
    __syncthreads();
    if (t < 8) { lbase[t] = atomicAdd(&bktcnt[t], lcnt[t]); lcur[t] = 0; }
    __syncthreads();
    if (val) {
        int rank = atomicAdd(&lcur[b], 1); // LDS
        int pos = lbase[b] + rank;
        if (pos < C0CAP) {
            keys[b * C0CAP + pos] = d;
            pay [b * C0CAP + pos] = r;
        }
    }
}

// hist0: block = bucket(0..7) x slice(0..7); 1024 bins owned exclusively ->
// LDS histogram, plain store to cnt0. grid layout: blockIdx = slice*8+bucket
// so bucket == blockIdx%8 (XCD-pinned).
__global__ __launch_bounds__(1024) void hist0_k(
    const int* __restrict__ keys, const int* __restrict__ bktcnt,
    int* __restrict__ cnt0)
{
    int bucket = blockIdx.x & 7;
    int sl     = blockIdx.x >> 3;
    int bin0   = bucket * 8192 + sl * 1024;
    __shared__ int h[1024];
    int t = threadIdx.x;
    h[t] = 0;
    __syncthreads();
    int m = min(bktcnt[bucket], C0CAP);
    const int* kp = keys + bucket * C0CAP;
    for (int j = t; j < m; j += 1024) {
        int k = __builtin_nontemporal_load(&kp[j]);
        unsigned rel = (unsigned)(k - bin0);
        if (rel < 1024u) atomicAdd(&h[rel], 1);   // LDS
    }
    __syncthreads();
    cnt0[bin0 + t] = h[t];
}

// scatter0: same block mapping; cursors (from rp0) in LDS; emit CSR records.
__global__ __launch_bounds__(1024) void scatter0_k(
    const int* __restrict__ keys, const float4* __restrict__ pay,
    const int* __restrict__ bktcnt, const int* __restrict__ rp0,
    float4* __restrict__ csr0)
{
    int bucket = blockIdx.x & 7;
    int sl     = blockIdx.x >> 3;
    int bin0   = bucket * 8192 + sl * 1024;
    __shared__ int cur[1024];
    int t = threadIdx.x;
    cur[t] = rp0[bin0 + t];
    __syncthreads();
    int m = min(bktcnt[bucket], C0CAP);
    const int*    kp = keys + bucket * C0CAP;
    const float4* pp = pay  + bucket * C0CAP;
    for (int j = t; j < m; j += 1024) {
        int k = __builtin_nontemporal_load(&kp[j]);
        unsigned rel = (unsigned)(k - bin0);
        if (rel < 1024u) {
            int p = atomicAdd(&cur[rel], 1);      // LDS
            csr0[p] = pp[j];
        }
    }
}

// conv0 (new path): thread-per-node, streams contiguous records.
__global__ __launch_bounds__(256) void conv0_k(
    const int* __restrict__ rp, const float4* __restrict__ csr,
    const float* __restrict__ w1, const float* __restrict__ b1,
    const float* __restrict__ w2, const float* __restrict__ b2,
    const float* __restrict__ root, const float* __restrict__ bias,
    const float* __restrict__ x, float* __restrict__ y)
{
    __shared__ float w1s[15], b1s[5], w2s[60], b2s[12], roots[12], biass[12];
    int t = threadIdx.x;
    if (t < 60) w2s[t] = w2[t];
    if (t < 15) w1s[t] = w1[t];
    if (t < 5)  b1s[t] = b1[t];
    if (t >= 64  && t < 76)  b2s[t - 64]   = b2[t - 64];
    if (t >= 128 && t < 140) roots[t - 128] = root[t - 128];
    if (t >= 192 && t < 204) biass[t - 192] = bias[t - 192];
    __syncthreads();
    int v = blockIdx.x * 256 + t;
    int r0 = rp[v], r1 = rp[v + 1];
    float S0 = 0.f, S1 = 0.f, S2 = 0.f, S3 = 0.f, S4 = 0.f, S5 = 0.f;
    for (int j = r0; j < r1; j++) {
        float4 r = csr[j];
        float h0 = tanhf(r.x * w1s[0] + r.y * w1s[5] + r.z * w1s[10] + b1s[0]);
        float h1 = tanhf(r.x * w1s[1] + r.y * w1s[6] + r.z * w1s[11] + b1s[1]);
        float h2 = tanhf(r.x * w1s[2] + r.y * w1s[7] + r.z * w1s[12] + b1s[2]);
        float h3 = tanhf(r.x * w1s[3] + r.y * w1s[8] + r.z * w1s[13] + b1s[3]);
        float h4 = tanhf(r.x * w1s[4] + r.y * w1s[9] + r.z * w1s[14] + b1s[4]);
        S0 += r.w;
        S1 += h0 * r.w; S2 += h1 * r.w; S3 += h2 * r.w;
        S4 += h3 * r.w; S5 += h4 * r.w;
    }
    float inv = 1.f / fmaxf((float)(r1 - r0), 1.f);
    float xv = x[v];
    #pragma unroll
    for (int o = 0; o < 12; o++) {
        float msg = b2s[o] * S0 + w2s[o] * S1 + w2s[12 + o] * S2 +
                    w2s[24 + o] * S3 + w2s[36 + o] * S4 + w2s[48 + o] * S5;
        y[v * 12 + o] = msg * inv + xv * roots[o] + biass[o];
    }
}

// ---------------------------------------------------------------------------
// hstats / wstats: closs via h-statistics (unchanged).
// ---------------------------------------------------------------------------
struct HArgs {
    const float* eattr[5];
    const float* w1[5];
    const float* b1[5];
    float*       H;
    int          E[5];
    int          bstart[6];
};

__global__ __launch_bounds__(256) void hstats_k(HArgs a) {
    const int K = 32;
    int b = blockIdx.x, l = 0;
    while (l < 4 && b >= a.bstart[l + 1]) l++;
    int bloc = b - a.bstart[l];
    const float* ea = a.eattr[l];
    float w1r[15], b1r[5];
    #pragma unroll
    for (int i = 0; i < 15; i++) w1r[i] = a.w1[l][i];
    #pragma unroll
    for (int i = 0; i < 5; i++)  b1r[i] = a.b1[l][i];
    float acc[20];
    #pragma unroll
    for (int i = 0; i < 20; i++) acc[i] = 0.f;
    int base = bloc * 256 * K + threadIdx.x;
    for (int it = 0; it < K; it++) {
        int e = base + it * 256;
        if (e < a.E[l]) {
            float e0 = ea[e * 3], e1 = ea[e * 3 + 1], e2 = ea[e * 3 + 2];
            float h[5];
            #pragma unroll
            for (int k = 0; k < 5; k++)
                h[k] = tanhf(e0 * w1r[k] + e1 * w1r[5 + k] + e2 * w1r[10 + k] + b1r[k]);
            int p = 5;
            #pragma unroll
            for (int k = 0; k < 5; k++) {
                acc[k] += h[k];
                #pragma unroll
                for (int k2 = k; k2 < 5; k2++) acc[p++] += h[k] * h[k2];
            }
        }
    }
    __shared__ float red[4][20];
    int wid = threadIdx.x >> 6, lane = threadIdx.x & 63;
    #pragma unroll
    for (int v = 0; v < 20; v++) {
        float s = acc[v];
        #pragma unroll
        for (int off = 32; off; off >>= 1) s += __shfl_down(s, off);
        if (lane == 0) red[wid][v] = s;
    }
    __syncthreads();
    if (threadIdx.x < 20) {
        float s = red[0][threadIdx.x] + red[1][threadIdx.x] +
                  red[2][threadIdx.x] + red[3][threadIdx.x];
        atomicAdd(&a.H[l * 20 + threadIdx.x], s);
    }
}

struct WArgs {
    const float* w2[5];
    const float* b2[5];
    const float* H;
    float*       sq;
    int          cico[5];
    int          E[5];
};

__global__ __launch_bounds__(64) void wstats_k(WArgs a) {
    int l = blockIdx.x;
    const float* w2 = a.w2[l];
    const float* b2 = a.b2[l];
    int cico = a.cico[l];
    float d[21];
    #pragma unroll
    for (int i = 0; i < 21; i++) d[i] = 0.f;
    for (int u = threadIdx.x; u < cico; u += 64) {
        float b = b2[u];
        float w[5];
        #pragma unroll
        for (int k = 0; k < 5; k++) w[k] = w2[k * cico + u];
        int p = 0;
        #pragma unroll
        for (int k = 0; k < 5; k++) {
            #pragma unroll
            for (int k2 = k; k2 < 5; k2++) d[p++] += w[k] * w[k2];
        }
        #pragma unroll
        for (int k = 0; k < 5; k++) d[15 + k] += b * w[k];
        d[20] += b * b;
    }
    #pragma unroll
    for (int i = 0; i < 21; i++) {
        #pragma unroll
        for (int off = 32; off; off >>= 1) d[i] += __shfl_down(d[i], off);
    }
    if (threadIdx.x == 0) {
        const float* H1 = a.H + l * 20;
        const float* H2 = H1 + 5;
        float sq = (float)a.E[l] * d[20];
        #pragma unroll
        for (int k = 0; k < 5; k++) sq += 2.f * d[15 + k] * H1[k];
        int p = 0;
        #pragma unroll
        for (int k = 0; k < 5; k++) {
            #pragma unroll
            for (int k2 = k; k2 < 5; k2++) {
                sq += ((k == k2) ? 1.f : 2.f) * d[p] * H2[p];
                p++;
            }
        }
        a.sq[l] = sq;
    }
}

// ---------------------------------------------------------------------------
// node_conv_k (L0 fallback path, eid-based).
// ---------------------------------------------------------------------------
template<int CI, int CO, int OW>
__global__ __launch_bounds__(256) void node_conv_k(
    int N,
    const int* __restrict__ rp, const int* __restrict__ eid,
    const int* __restrict__ src, const float* __restrict__ eattr,
    const float* __restrict__ w1, const float* __restrict__ b1,
    const float* __restrict__ w2, const float* __restrict__ b2,
    const float* __restrict__ root, const float* __restrict__ bias,
    const float* __restrict__ x, float* __restrict__ y)
{
    constexpr int G    = CO / OW;
    constexpr int CICO = CI * CO;
    __shared__ float w1s[15], b1s[5];
    __shared__ float w2s[5 * CICO], b2s[CICO], roots[CICO], biass[CO];
    for (int t = threadIdx.x; t < 5 * CICO; t += 256) w2s[t]   = w2[t];
    for (int t = threadIdx.x; t < CICO;     t += 256) b2s[t]   = b2[t];
    for (int t = threadIdx.x; t < CICO;     t += 256) roots[t] = root[t];
    for (int t = threadIdx.x; t < CO;       t += 256) biass[t] = bias[t];
    if (threadIdx.x < 15) w1s[threadIdx.x] = w1[threadIdx.x];
    if (threadIdx.x < 5)  b1s[threadIdx.x] = b1[threadIdx.x];
    __syncthreads();

    int t = blockIdx.x * 256 + threadIdx.x;
    if (t >= N * G) return;
    int v  = t / G;
    int ob = (t % G) * OW;
    int r0 = rp[v], r1 = rp[v + 1];
    int d  = r1 - r0;
    float acc[OW];
    #pragma unroll
    for (int oo = 0; oo < OW; oo++) acc[oo] = 0.f;
    for (int j = r0; j < r1; j++) {
        int e = eid[j];
        float ea0 = eattr[e * 3], ea1 = eattr[e * 3 + 1], ea2 = eattr[e * 3 + 2];
        float h[5];
        #pragma unroll
        for (int k = 0; k < 5; k++)
            h[k] = tanhf(ea0 * w1s[k] + ea1 * w1s[5 + k] + ea2 * w1s[10 + k] + b1s[k]);
        int sv = src[e];
        for (int i = 0; i < CI; i++) {
            float xi = x[sv * CI + i];
            #pragma unroll
            for (int oo = 0; oo < OW; oo++) {
                int o = ob + oo;
                float we = b2s[i * CO + o];
                #pragma unroll
                for (int k = 0; k < 5; k++) we += h[k] * w2s[k * CICO + i * CO + o];
                acc[oo] += xi * we;
            }
        }
    }
    float inv = 1.f / fmaxf((float)d, 1.f);
    #pragma unroll
    for (int oo = 0; oo < OW; oo++) acc[oo] *= inv;
    for (int i = 0; i < CI; i++) {
        float xi = x[v * CI + i];
        #pragma unroll
        for (int oo = 0; oo < OW; oo++)
            acc[oo] += xi * roots[i * CO + ob + oo];
    }
    #pragma unroll
    for (int oo = 0; oo < OW; oo++)
        y[(size_t)v * CO + ob + oo] = acc[oo] + biass[ob + oo];
}

// ---------------------------------------------------------------------------
// coop_conv_k (L1-L4): one block per node (unchanged).
// ---------------------------------------------------------------------------
template<int CI, int CO>
__global__ __launch_bounds__(256) void coop_conv_k(
    const int* __restrict__ rp, const int* __restrict__ eid,
    const int* __restrict__ src, const float* __restrict__ eattr,
    const float* __restrict__ w1, const float* __restrict__ b1,
    const float* __restrict__ w2, const float* __restrict__ b2,
    const float* __restrict__ root, const float* __restrict__ bias,
    const float* __restrict__ x, float* __restrict__ y)
{
    constexpr int CH   = 48;
    constexpr int CICO = CI * CO;
    static_assert(6 * CI <= 256, "phase-A lanes");
    __shared__ float w1s[20];
    __shared__ int   eb[CH], svb[CH];
    __shared__ float hb[CH * 6];
    __shared__ float xs[CH * CI];
    __shared__ float S[6 * CI];

    int t = threadIdx.x;
    int v = blockIdx.x;
    if (t < 20) w1s[t] = (t < 15) ? w1[t] : b1[t - 15];
    int r0 = rp[v], r1 = rp[v + 1];
    int d  = r1 - r0;
    float acc = 0.f;

    for (int c0 = r0; c0 < r1; c0 += CH) {
        int cn = min(CH, r1 - c0);
        if (t < cn) {
            int e = eid[c0 + t];
            eb[t]  = e;
            svb[t] = src[e];
            hb[t * 6] = 1.f;
        }
        __syncthreads();
        if (t < cn * 5) {
            int j = t / 5, k = t % 5;
            int e = eb[j];
            float e0 = eattr[e * 3], e1 = eattr[e * 3 + 1], e2 = eattr[e * 3 + 2];
            hb[j * 6 + 1 + k] =
                tanhf(e0 * w1s[k] + e1 * w1s[5 + k] + e2 * w1s[10 + k] + w1s[15 + k]);
        }
        for (int u = t; u < cn * CI; u += 256)
            xs[u] = x[(size_t)svb[u / CI] * CI + (u % CI)];
        __syncthreads();
        if (t < 6 * CI) {
            int i = t / 6, k6 = t % 6;
            for (int j = 0; j < cn; j++)
                acc += hb[j * 6 + k6] * xs[j * CI + i];
        }
        __syncthreads();
    }

    if (t < 6 * CI) S[t] = acc;
    __syncthreads();

    if (t < CO) {
        float m = 0.f;
        for (int i = 0; i < CI; i++) {
            m += b2[i * CO + t] * S[i * 6];
            #pragma unroll
            for (int k = 0; k < 5; k++)
                m += w2[k * CICO + i * CO + t] * S[i * 6 + 1 + k];
        }
        m /= fmaxf((float)d, 1.f);
        for (int i = 0; i < CI; i++)
            m += x[(size_t)v * CI + i] * root[i * CO + t];
        y[(size_t)v * CO + t] = m + bias[t];
    }
}

// ---------------------------------------------------------------------------
// pool_k (unchanged).
// ---------------------------------------------------------------------------
template<int CO>
__global__ __launch_bounds__(256) void pool_k(
    int NN,
    const int* __restrict__ crp, const int* __restrict__ cnid,
    const float* __restrict__ y, const float* __restrict__ pos,
    float* __restrict__ xn, float* __restrict__ pn)
{
    int t = blockIdx.x * 256 + threadIdx.x;
    if (t >= NN * (CO + 3)) return;
    int c = t / (CO + 3), o = t % (CO + 3);
    int r0 = crp[c], r1 = crp[c + 1];
    int d = r1 - r0;
    if (o < CO) {
        float m = -INFINITY;
        for (int j = r0; j < r1; j++)
            m = fmaxf(m, y[(size_t)cnid[j] * CO + o]);
        if (d == 0 || !isfinite(m)) m = 0.f;
        xn[c * (CO + 3) + o] = m;
    } else {
        int k = o - CO;
        float sum = 0.f;
        for (int j = r0; j < r1; j++)
            sum += pos[cnid[j] * 3 + k];
        float pm = sum / fmaxf((float)d, 1.f);
        xn[c * (CO + 3) + CO + k] = pm;
        pn[c * 3 + k] = pm;
    }
}

// ---------------------------------------------------------------------------
// fc_k (unchanged).
// ---------------------------------------------------------------------------
__global__ __launch_bounds__(128) void fc_k(
    const float* __restrict__ x5,
    const float* __restrict__ fc_w, const float* __restrict__ fc_b,
    const float* __restrict__ sq, float* __restrict__ out)
{
    __shared__ float feat[8 * 376];
    __shared__ float logit[80];
    __shared__ float roff[8];
    for (int t = threadIdx.x; t < 8 * 376; t += 128) feat[t] = x5[t];
    __syncthreads();
    int t = threadIdx.x;
    if (t < 80) {
        int b = t / 10, j = t % 10;
        float acc = fc_b[j];
        for (int k = 0; k < 376; k++) acc += feat[b * 376 + k] * fc_w[k * 10 + j];
        logit[t] = acc;
    }
    __syncthreads();
    if (t < 8) {
        float m = -1e30f;
        for (int j = 0; j < 10; j++) m = fmaxf(m, logit[t * 10 + j]);
        float ssum = 0.f;
        for (int j = 0; j < 10; j++) ssum += expf(logit[t * 10 + j] - m);
        roff[t] = m + logf(ssum);
    }
    __syncthreads();
    if (t < 80) out[t] = logit[t] - roff[t / 10];
    if (t == 0) {
        float closs = 0.f;
        closs += sq[0] * (1.0f / 12582912.0f);
        closs += sq[1] * (1.0f / 78643200.0f);
        closs += sq[2] * (1.0f / 42205184.0f);
        closs += sq[3] * (1.0f / 18284544.0f);
        closs += sq[4] * (1.0f / 7028736.0f);
        out[80] = closs;
    }
}

// ---------------------------------------------------------------------------

extern "C" void kernel_launch(void* const* d_in, const int* in_sizes, int n_in,
                              void* d_out, int out_size, void* d_ws, size_t ws_size,
                              hipStream_t stream)
{
    static const int NSa[6] = {65536, 16384, 4096, 1024, 256, 64};
    static const int ESa[5] = {1048576, 262144, 65536, 16384, 4096};
    static const int COa[5] = {12, 20, 28, 36, 44};
    static const int CIa[5] = {1, 15, 23, 31, 39};

    const float* x0   = (const float*)d_in[0];
    const float* pos0 = (const float*)d_in[1];

    // ---- workspace layout (words). Base ~12 MB; new-path extras ~38 MB ----
    int* wsw = (int*)d_ws;
    size_t off = 0;
    auto alw = [&](size_t n) -> size_t {
        size_t p = off; off += (n + 63) & ~(size_t)63; return p;
    };
    size_t degO[5], cdegO[5];
    for (int l = 0; l < 5; l++) degO[l]  = alw(NSa[l]);
    for (int l = 0; l < 5; l++) cdegO[l] = alw(NSa[l + 1]);
    size_t HO  = alw(100);
    size_t bkO = alw(8);                           // seg0 bucket counters
    size_t zeroWords = off;
    size_t rpO[5], crpO[5], eidO[5], cnidO[5];
    for (int l = 0; l < 5; l++) rpO[l]   = alw(NSa[l] + 1);
    for (int l = 0; l < 5; l++) crpO[l]  = alw(NSa[l + 1] + 1);
    for (int l = 0; l < 5; l++) eidO[l]  = alw(ESa[l]);  // eid0 used only in fallback
    for (int l = 0; l < 5; l++) cnidO[l] = alw(NSa[l]);
    size_t tsO = alw(64);
    size_t toO = alw(64);
    size_t yO  = alw((size_t)65536 * 12);
    size_t sqO = alw(8);
    size_t xnO[5], pnO[5];
    for (int l = 0; l < 5; l++) xnO[l] = alw((size_t)NSa[l + 1] * (COa[l] + 3));
    for (int l = 0; l < 5; l++) pnO[l] = alw((size_t)NSa[l + 1] * 3);
    // new-path extras
    size_t keysO = alw((size_t)NBUCK * C0CAP);
    size_t payO  = alw((size_t)NBUCK * C0CAP * 4);
    size_t csr0O = alw((size_t)ESa[0] * 4);
    size_t needNew = off * 4;
    bool useNew = (ws_size >= needNew);

    hipMemsetAsync(d_ws, 0, zeroWords * 4, stream);

    // ---- scan descriptor: always all 10 segments ----
    SegArgs saAll{};
    for (int l = 0; l < 5; l++) {
        saAll.idx[l] = (const int*)d_in[3 + 10 * l];
        saAll.cnt[l] = wsw + degO[l];
        saAll.rp [l] = wsw + rpO[l];
        saAll.out[l] = wsw + eidO[l];
        saAll.n  [l] = ESa[l];
        saAll.nb [l] = NSa[l];
        saAll.idx[5 + l] = (const int*)d_in[5 + 10 * l];
        saAll.cnt[5 + l] = wsw + cdegO[l];
        saAll.rp [5 + l] = wsw + crpO[l];
        saAll.out[5 + l] = wsw + cnidO[l];
        saAll.n  [5 + l] = NSa[l];
        saAll.nb [5 + l] = NSa[l + 1];
    }
    ScanAux sx{};
    int btiles = 0;
    for (int s = 0; s < 10; s++) {
        sx.sstart[s] = btiles;
        btiles += (saAll.nb[s] + 4095) / 4096;
    }
    sx.sstart[10] = btiles;
    sx.T = btiles;
    sx.tilesum = wsw + tsO;
    sx.tileoff = wsw + toO;

    // ---- hist/scatter descriptor: segs 1-9 (new) or all 10 (fallback) ----
    SegArgs saHS{};
    int nseg = 0;
    int firstEdgeSeg = useNew ? 1 : 0;             // seg0 handled by radix path
    for (int l = firstEdgeSeg; l < 5; l++) {
        saHS.idx[nseg] = (const int*)d_in[3 + 10 * l];
        saHS.cnt[nseg] = wsw + degO[l];
        saHS.rp [nseg] = wsw + rpO[l];
        saHS.out[nseg] = wsw + eidO[l];
        saHS.n  [nseg] = ESa[l];
        saHS.nb [nseg] = NSa[l];
        nseg++;
    }
    for (int l = 0; l < 5; l++) {
        saHS.idx[nseg] = (const int*)d_in[5 + 10 * l];
        saHS.cnt[nseg] = wsw + cdegO[l];
        saHS.rp [nseg] = wsw + crpO[l];
        saHS.out[nseg] = wsw + cnidO[l];
        saHS.n  [nseg] = NSa[l];
        saHS.nb [nseg] = NSa[l + 1];
        nseg++;
    }
    int tiles = 0;
    for (int s = 0; s < nseg; s++) {
        int lg = 31 - __builtin_clz(saHS.nb[s]);
        saHS.shift[s] = lg - 3;
        saHS.tstart[s] = tiles;
        tiles += (saHS.n[s] + 255) / 256;
    }
    for (int s = nseg; s <= 10; s++) {
        saHS.tstart[s] = tiles;
        if (s < 10) {                              // padded, never dereferenced
            saHS.idx[s] = saHS.idx[nseg - 1]; saHS.cnt[s] = saHS.cnt[nseg - 1];
            saHS.rp[s] = saHS.rp[nseg - 1];   saHS.out[s] = saHS.out[nseg - 1];
            saHS.n[s] = 0; saHS.nb[s] = 8; saHS.shift[s] = 0;
        }
    }

    int*    keys0 = wsw + keysO;
    float4* pay0  = (float4*)(wsw + payO);
    float4* csr0  = (float4*)(wsw + csr0O);
    int*    bkt0  = wsw + bkO;

    if (useNew) {
        part0_k<<<ESa[0] / 256, 256, 0, stream>>>(
            (const int*)d_in[2], (const int*)d_in[3], (const float*)d_in[4],
            x0, keys0, pay0, bkt0, ESa[0]);
        hist0_k<<<64, 1024, 0, stream>>>(keys0, bkt0, wsw + degO[0]);
    }
    hist_all_k<<<tiles * NBUCK, 256, 0, stream>>>(saHS);
    scanA_k<<<btiles, 256, 0, stream>>>(saAll, sx);
    scanB_k<<<1, 64, 0, stream>>>(saAll, sx);
    scanC_k<<<btiles, 256, 0, stream>>>(saAll, sx);
    if (useNew)
        scatter0_k<<<64, 1024, 0, stream>>>(keys0, pay0, bkt0, wsw + rpO[0], csr0);
    scatter_all_k<<<tiles * NBUCK, 256, 0, stream>>>(saHS);

    // ---- closs statistics ----
    HArgs ha{};
    int bs = 0;
    for (int l = 0; l < 5; l++) {
        ha.eattr[l] = (const float*)d_in[4 + 10 * l];
        ha.w1[l]    = (const float*)d_in[6 + 10 * l];
        ha.b1[l]    = (const float*)d_in[7 + 10 * l];
        ha.E[l]     = ESa[l];
        ha.bstart[l] = bs;
        bs += (ESa[l] + 256 * 32 - 1) / (256 * 32);
    }
    ha.bstart[5] = bs;
    ha.H = (float*)(wsw + HO);
    hstats_k<<<bs, 256, 0, stream>>>(ha);

    WArgs wa{};
    for (int l = 0; l < 5; l++) {
        wa.w2[l]   = (const float*)d_in[8 + 10 * l];
        wa.b2[l]   = (const float*)d_in[9 + 10 * l];
        wa.cico[l] = CIa[l] * COa[l];
        wa.E[l]    = ESa[l];
    }
    wa.H  = (const float*)(wsw + HO);
    wa.sq = (float*)(wsw + sqO);
    wstats_k<<<5, 64, 0, stream>>>(wa);

    float* yb = (float*)(wsw + yO);

    // ---- level 0 conv ----
    if (useNew) {
        conv0_k<<<NSa[0] / 256, 256, 0, stream>>>(
            wsw + rpO[0], csr0,
            (const float*)d_in[6], (const float*)d_in[7],
            (const float*)d_in[8], (const float*)d_in[9],
            (const float*)d_in[10], (const float*)d_in[11], x0, yb);
    } else {
        node_conv_k<1, 12, 6><<<(NSa[0] * 2 + 255) / 256, 256, 0, stream>>>(
            NSa[0], wsw + rpO[0], wsw + eidO[0],
            (const int*)d_in[2], (const float*)d_in[4],
            (const float*)d_in[6], (const float*)d_in[7],
            (const float*)d_in[8], (const float*)d_in[9],
            (const float*)d_in[10], (const float*)d_in[11], x0, yb);
    }
    pool_k<12><<<(NSa[1] * 15 + 255) / 256, 256, 0, stream>>>(
        NSa[1], wsw + crpO[0], wsw + cnidO[0], yb, pos0,
        (float*)(wsw + xnO[0]), (float*)(wsw + pnO[0]));

    // ---- levels 1-4 ----
#define LVLC(l, CI_, CO_) do {                                                 \
    const float* xin   = (const float*)(wsw + xnO[(l) - 1]);                   \
    const float* posin = (const float*)(wsw + pnO[(l) - 1]);                   \
    int N = NSa[(l)], NN = NSa[(l) + 1];                                       \
    coop_conv_k<CI_, CO_><<<N, 256, 0, stream>>>(                              \
        wsw + rpO[(l)], wsw + eidO[(l)],                                       \
        (const int*)d_in[2 + 10 * (l)], (const float*)d_in[4 + 10 * (l)],      \
        (const float*)d_in[6 + 10 * (l)], (const float*)d_in[7 + 10 * (l)],    \
        (const float*)d_in[8 + 10 * (l)], (const float*)d_in[9 + 10 * (l)],    \
        (const float*)d_in[10 + 10 * (l)], (const float*)d_in[11 + 10 * (l)],  \
        xin, yb);                                                              \
    pool_k<CO_><<<(NN * ((CO_) + 3) + 255) / 256, 256, 0, stream>>>(           \
        NN, wsw + crpO[(l)], wsw + cnidO[(l)], yb, posin,                      \
        (float*)(wsw + xnO[(l)]), (float*)(wsw + pnO[(l)]));                   \
} while (0)

    LVLC(1, 15, 20);
    LVLC(2, 23, 28);
    LVLC(3, 31, 36);
    LVLC(4, 39, 44);
#undef LVLC

    fc_k<<<1, 128, 0, stream>>>((const float*)(wsw + xnO[4]),
                                (const float*)d_in[52], (const float*)d_in[53],
                                (const float*)(wsw + sqO), (float*)d_out);
}

// Round 9
// 491.175 us; speedup vs baseline: 1.2712x; 1.2712x over previous
//
#include <hip/hip_runtime.h>
#include <math.h>

// ---------------------------------------------------------------------------
// Net_37512244363273: 5-level edge-conditioned graph conv + voxel pooling + FC
// Round 9: round 8's scatter0 (64 blocks, 8x bucket rescans, 10% occupancy,
// 99 us) replaced by a deterministic matrix-scan radix partition for seg 0:
//   cnt0 (256 tiles, LDS 128-bucket hist -> M[tile][bucket])
//   colscan (128 blocks, per-bucket scan over tiles) + bktscan (bases)
//   part0 (256 tiles, LDS cursors seeded from M2 -> records written once)
//   bucket0 (128 blocks own one contiguous bucket each: LDS 512-bin hist +
//            scan -> rp0 + CSR records; single pass, no rescans)
// Zero atomics in seg0 placement (LDS ranking only, deterministic bases).
// Segs 1-9 keep the round-7 XCD-bucketed atomic path. conv0 streams the
// packed (ea, x[src]) records. Output: 80 log_softmax + closs = 81 floats.
// ---------------------------------------------------------------------------

#define NBUCK 8
#define TILES0 256                 // 1048576 / 4096

// ---- segment descriptor for CSR builds (segs 1-9: edge 1-4 + cluster 0-4) --
struct SegArgs {
    const int* idx[10];
    int*       cnt[10];
    int*       rp [10];
    int*       out[10];
    int        n  [10];
    int        nb [10];
    int        shift[10];
    int        tstart[11];
};

struct ScanAux {
    int* tilesum;
    int* tileoff;
    int  sstart[11];
    int  T;
};

// XCD-bucketed histogram (per-element global atomics; small segs only).
__global__ __launch_bounds__(256) void hist_all_k(SegArgs a) {
    int B = blockIdx.x;
    int bucket = B % NBUCK;
    int T = B / NBUCK;
    int s = 0;
    while (s < 9 && T >= a.tstart[s + 1]) s++;
    int i = (T - a.tstart[s]) * 256 + threadIdx.x;
    if (i >= a.n[s]) return;
    int d = a.idx[s][i];
    if ((d >> a.shift[s]) != bucket) return;
    atomicAdd(&a.cnt[s][d], 1);
}

// 3-phase hierarchical scan over segs 1-9 cnt arrays.
__global__ __launch_bounds__(256) void scanA_k(SegArgs a, ScanAux x) {
    int b = blockIdx.x;
    int s = 0;
    while (s < 9 && b >= x.sstart[s + 1]) s++;
    int tloc = b - x.sstart[s];
    int nb = a.nb[s];
    const int* cnt = a.cnt[s];
    int i0 = tloc * 4096 + threadIdx.x * 16;
    int sum = 0;
    #pragma unroll
    for (int k = 0; k < 16; k++) {
        int i = i0 + k;
        if (i < nb) sum += cnt[i];
    }
    #pragma unroll
    for (int o = 32; o; o >>= 1) sum += __shfl_down(sum, o);
    __shared__ int red[4];
    if ((threadIdx.x & 63) == 0) red[threadIdx.x >> 6] = sum;
    __syncthreads();
    if (threadIdx.x == 0)
        x.tilesum[b] = red[0] + red[1] + red[2] + red[3];
}

__global__ __launch_bounds__(64) void scanB_k(SegArgs a, ScanAux x) {
    int lane = threadIdx.x;
    int orig = (lane < x.T) ? x.tilesum[lane] : 0;
    int val = orig;
    #pragma unroll
    for (int d = 1; d < 64; d <<= 1) {
        int v = __shfl_up(val, d);
        if (lane >= d) val += v;
    }
    int excl = val - orig;
    int s = 0;
    while (s < 9 && lane >= x.sstart[s + 1]) s++;
    int segExcl = __shfl(excl, x.sstart[s]);
    if (lane < x.T) {
        x.tileoff[lane] = excl - segExcl;
        if (lane == x.sstart[s + 1] - 1)
            a.rp[s][a.nb[s]] = val - segExcl;
    }
}

__global__ __launch_bounds__(256) void scanC_k(SegArgs a, ScanAux x) {
    int b = blockIdx.x;
    int s = 0;
    while (s < 9 && b >= x.sstart[s + 1]) s++;
    int tloc = b - x.sstart[s];
    int nb = a.nb[s];
    const int* cnt = a.cnt[s];
    int* rp = a.rp[s];
    int i0 = tloc * 4096 + threadIdx.x * 16;
    int v[16];
    int sum = 0;
    #pragma unroll
    for (int k = 0; k < 16; k++) {
        int i = i0 + k;
        v[k] = (i < nb) ? cnt[i] : 0;
        sum += v[k];
    }
    __shared__ int sc[256];
    int acc = sum;
    sc[threadIdx.x] = acc;
    __syncthreads();
    for (int d = 1; d < 256; d <<= 1) {
        int t2 = (threadIdx.x >= d) ? sc[threadIdx.x - d] : 0;
        __syncthreads();
        acc += t2;
        sc[threadIdx.x] = acc;
        __syncthreads();
    }
    int running = x.tileoff[b] + (acc - sum);
    #pragma unroll
    for (int k = 0; k < 16; k++) {
        int i = i0 + k;
        if (i < nb) rp[i] = running;
        running += v[k];
    }
}

// XCD-bucketed countdown-scatter (small segs only).
__global__ __launch_bounds__(256) void scatter_all_k(SegArgs a) {
    int B = blockIdx.x;
    int bucket = B % NBUCK;
    int T = B / NBUCK;
    int s = 0;
    while (s < 9 && T >= a.tstart[s + 1]) s++;
    int i = (T - a.tstart[s]) * 256 + threadIdx.x;
    if (i >= a.n[s]) return;
    int d = a.idx[s][i];
    if ((d >> a.shift[s]) != bucket) return;
    int p = atomicSub(&a.cnt[s][d], 1) - 1;
    a.out[s][a.rp[s][d] + p] = i;
}

// ---------------------------------------------------------------------------
// Seg-0 deterministic radix CSR build (128 buckets of 512 bins; no global
// atomics anywhere; placement bases come from a tile x bucket matrix scan).
// ---------------------------------------------------------------------------
__global__ __launch_bounds__(256) void cnt0_k(
    const int* __restrict__ dst, int* __restrict__ M)
{
    __shared__ int h[128];
    int t = threadIdx.x;
    if (t < 128) h[t] = 0;
    __syncthreads();
    int base = blockIdx.x * 4096 + t;
    #pragma unroll
    for (int it = 0; it < 16; it++)
        atomicAdd(&h[dst[base + it * 256] >> 9], 1);      // LDS
    __syncthreads();
    if (t < 128) M[blockIdx.x * 128 + t] = h[t];
}

// per-bucket exclusive scan over the 256 tiles.
__global__ __launch_bounds__(256) void colscan_k(
    const int* __restrict__ M, int* __restrict__ M2, int* __restrict__ colTotal)
{
    int b = blockIdx.x, t = threadIdx.x;
    int v = M[t * 128 + b];
    __shared__ int sc[256];
    sc[t] = v;
    __syncthreads();
    for (int d = 1; d < 256; d <<= 1) {
        int u = (t >= d) ? sc[t - d] : 0;
        __syncthreads();
        sc[t] += u;
        __syncthreads();
    }
    M2[t * 128 + b] = sc[t] - v;
    if (t == 255) colTotal[b] = sc[255];
}

__global__ __launch_bounds__(128) void bktscan_k(
    const int* __restrict__ colTotal, int* __restrict__ bucketStart,
    int* __restrict__ rp0)
{
    int t = threadIdx.x;
    int v = colTotal[t];
    __shared__ int sc[128];
    sc[t] = v;
    __syncthreads();
    for (int d = 1; d < 128; d <<= 1) {
        int u = (t >= d) ? sc[t - d] : 0;
        __syncthreads();
        sc[t] += u;
        __syncthreads();
    }
    bucketStart[t] = sc[t] - v;
    if (t == 127) { bucketStart[128] = sc[127]; rp0[65536] = sc[127]; }
}

// partition: write (key, record) into bucket-segregated staging; slots are
// deterministic (bucketStart + within-bucket tile prefix + LDS rank).
__global__ __launch_bounds__(256) void part0_k(
    const int* __restrict__ src, const int* __restrict__ dst,
    const float* __restrict__ ea, const float* __restrict__ x0,
    const int* __restrict__ M2, const int* __restrict__ bucketStart,
    int* __restrict__ keys, float4* __restrict__ pay)
{
    __shared__ int cur[128];
    int t = threadIdx.x;
    if (t < 128) cur[t] = bucketStart[t] + M2[blockIdx.x * 128 + t];
    __syncthreads();
    int base = blockIdx.x * 4096 + t;
    #pragma unroll
    for (int it = 0; it < 16; it++) {
        int i = base + it * 256;
        int d = dst[i];
        float4 r;
        r.x = ea[i * 3]; r.y = ea[i * 3 + 1]; r.z = ea[i * 3 + 2];
        r.w = x0[src[i]];
        int p = atomicAdd(&cur[d >> 9], 1);               // LDS
        keys[p] = d;
        pay [p] = r;
    }
}

// one block per bucket: LDS 512-bin hist + scan -> rp0 + CSR records.
__global__ __launch_bounds__(1024) void bucket0_k(
    const int* __restrict__ keys, const float4* __restrict__ pay,
    const int* __restrict__ bucketStart,
    int* __restrict__ rp0, float4* __restrict__ csr0)
{
    int b = blockIdx.x;
    int lo = bucketStart[b], hi = bucketStart[b + 1];
    int bin0 = b << 9;
    __shared__ int hist[512], cur[512], sc[512];
    int t = threadIdx.x;
    if (t < 512) hist[t] = 0;
    __syncthreads();
    for (int j = lo + t; j < hi; j += 1024)
        atomicAdd(&hist[keys[j] - bin0], 1);              // LDS
    __syncthreads();
    int v = (t < 512) ? hist[t] : 0;
    if (t < 512) sc[t] = v;
    __syncthreads();
    for (int d = 1; d < 512; d <<= 1) {
        int u = (t < 512 && t >= d) ? sc[t - d] : 0;
        __syncthreads();
        if (t < 512) sc[t] += u;
        __syncthreads();
    }
    if (t < 512) {
        int base = lo + sc[t] - v;                        // exclusive
        rp0[bin0 + t] = base;
        cur[t] = base;
    }
    __syncthreads();
    for (int j = lo + t; j < hi; j += 1024) {
        int rel = keys[j] - bin0;
        int p = atomicAdd(&cur[rel], 1);                  // LDS
        csr0[p] = pay[j];
    }
}

// conv0: thread-per-node, streams contiguous (ea, x[src]) records.
__global__ __launch_bounds__(256) void conv0_k(
    const int* __restrict__ rp, const float4* __restrict__ csr,
    const float* __restrict__ w1, const float* __restrict__ b1,
    const float* __restrict__ w2, const float* __restrict__ b2,
    const float* __restrict__ root, const float* __restrict__ bias,
    const float* __restrict__ x, float* __restrict__ y)
{
    __shared__ float w1s[15], b1s[5], w2s[60], b2s[12], roots[12], biass[12];
    int t = threadIdx.x;
    if (t < 60) w2s[t] = w2[t];
    if (t < 15) w1s[t] = w1[t];
    if (t < 5)  b1s[t] = b1[t];
    if (t >= 64  && t < 76)  b2s[t - 64]    = b2[t - 64];
    if (t >= 128 && t < 140) roots[t - 128] = root[t - 128];
    if (t >= 192 && t < 204) biass[t - 192] = bias[t - 192];
    __syncthreads();
    int v = blockIdx.x * 256 + t;
    int r0 = rp[v], r1 = rp[v + 1];
    float S0 = 0.f, S1 = 0.f, S2 = 0.f, S3 = 0.f, S4 = 0.f, S5 = 0.f;
    for (int j = r0; j < r1; j++) {
        float4 r = csr[j];
        float h0 = tanhf(r.x * w1s[0] + r.y * w1s[5] + r.z * w1s[10] + b1s[0]);
        float h1 = tanhf(r.x * w1s[1] + r.y * w1s[6] + r.z * w1s[11] + b1s[1]);
        float h2 = tanhf(r.x * w1s[2] + r.y * w1s[7] + r.z * w1s[12] + b1s[2]);
        float h3 = tanhf(r.x * w1s[3] + r.y * w1s[8] + r.z * w1s[13] + b1s[3]);
        float h4 = tanhf(r.x * w1s[4] + r.y * w1s[9] + r.z * w1s[14] + b1s[4]);
        S0 += r.w;
        S1 += h0 * r.w; S2 += h1 * r.w; S3 += h2 * r.w;
        S4 += h3 * r.w; S5 += h4 * r.w;
    }
    float inv = 1.f / fmaxf((float)(r1 - r0), 1.f);
    float xv = x[v];
    #pragma unroll
    for (int o = 0; o < 12; o++) {
        float msg = b2s[o] * S0 + w2s[o] * S1 + w2s[12 + o] * S2 +
                    w2s[24 + o] * S3 + w2s[36 + o] * S4 + w2s[48 + o] * S5;
        y[v * 12 + o] = msg * inv + xv * roots[o] + biass[o];
    }
}

// ---------------------------------------------------------------------------
// hstats / wstats: closs via h-statistics (all 5 levels, unchanged).
// ---------------------------------------------------------------------------
struct HArgs {
    const float* eattr[5];
    const float* w1[5];
    const float* b1[5];
    float*       H;
    int          E[5];
    int          bstart[6];
};

__global__ __launch_bounds__(256) void hstats_k(HArgs a) {
    const int K = 32;
    int b = blockIdx.x, l = 0;
    while (l < 4 && b >= a.bstart[l + 1]) l++;
    int bloc = b - a.bstart[l];
    const float* ea = a.eattr[l];
    float w1r[15], b1r[5];
    #pragma unroll
    for (int i = 0; i < 15; i++) w1r[i] = a.w1[l][i];
    #pragma unroll
    for (int i = 0; i < 5; i++)  b1r[i] = a.b1[l][i];
    float acc[20];
    #pragma unroll
    for (int i = 0; i < 20; i++) acc[i] = 0.f;
    int base = bloc * 256 * K + threadIdx.x;
    for (int it = 0; it < K; it++) {
        int e = base + it * 256;
        if (e < a.E[l]) {
            float e0 = ea[e * 3], e1 = ea[e * 3 + 1], e2 = ea[e * 3 + 2];
            float h[5];
            #pragma unroll
            for (int k = 0; k < 5; k++)
                h[k] = tanhf(e0 * w1r[k] + e1 * w1r[5 + k] + e2 * w1r[10 + k] + b1r[k]);
            int p = 5;
            #pragma unroll
            for (int k = 0; k < 5; k++) {
                acc[k] += h[k];
                #pragma unroll
                for (int k2 = k; k2 < 5; k2++) acc[p++] += h[k] * h[k2];
            }
        }
    }
    __shared__ float red[4][20];
    int wid = threadIdx.x >> 6, lane = threadIdx.x & 63;
    #pragma unroll
    for (int v = 0; v < 20; v++) {
        float s = acc[v];
        #pragma unroll
        for (int off = 32; off; off >>= 1) s += __shfl_down(s, off);
        if (lane == 0) red[wid][v] = s;
    }
    __syncthreads();
    if (threadIdx.x < 20) {
        float s = red[0][threadIdx.x] + red[1][threadIdx.x] +
                  red[2][threadIdx.x] + red[3][threadIdx.x];
        atomicAdd(&a.H[l * 20 + threadIdx.x], s);
    }
}

struct WArgs {
    const float* w2[5];
    const float* b2[5];
    const float* H;
    float*       sq;
    int          cico[5];
    int          E[5];
};

__global__ __launch_bounds__(64) void wstats_k(WArgs a) {
    int l = blockIdx.x;
    const float* w2 = a.w2[l];
    const float* b2 = a.b2[l];
    int cico = a.cico[l];
    float d[21];
    #pragma unroll
    for (int i = 0; i < 21; i++) d[i] = 0.f;
    for (int u = threadIdx.x; u < cico; u += 64) {
        float b = b2[u];
        float w[5];
        #pragma unroll
        for (int k = 0; k < 5; k++) w[k] = w2[k * cico + u];
        int p = 0;
        #pragma unroll
        for (int k = 0; k < 5; k++) {
            #pragma unroll
            for (int k2 = k; k2 < 5; k2++) d[p++] += w[k] * w[k2];
        }
        #pragma unroll
        for (int k = 0; k < 5; k++) d[15 + k] += b * w[k];
        d[20] += b * b;
    }
    #pragma unroll
    for (int i = 0; i < 21; i++) {
        #pragma unroll
        for (int off = 32; off; off >>= 1) d[i] += __shfl_down(d[i], off);
    }
    if (threadIdx.x == 0) {
        const float* H1 = a.H + l * 20;
        const float* H2 = H1 + 5;
        float sq = (float)a.E[l] * d[20];
        #pragma unroll
        for (int k = 0; k < 5; k++) sq += 2.f * d[15 + k] * H1[k];
        int p = 0;
        #pragma unroll
        for (int k = 0; k < 5; k++) {
            #pragma unroll
            for (int k2 = k; k2 < 5; k2++) {
                sq += ((k == k2) ? 1.f : 2.f) * d[p] * H2[p];
                p++;
            }
        }
        a.sq[l] = sq;
    }
}

// ---------------------------------------------------------------------------
// coop_conv_k (L1-L4): one block per node (unchanged).
// ---------------------------------------------------------------------------
template<int CI, int CO>
__global__ __launch_bounds__(256) void coop_conv_k(
    const int* __restrict__ rp, const int* __restrict__ eid,
    const int* __restrict__ src, const float* __restrict__ eattr,
    const float* __restrict__ w1, const float* __restrict__ b1,
    const float* __restrict__ w2, const float* __restrict__ b2,
    const float* __restrict__ root, const float* __restrict__ bias,
    const float* __restrict__ x, float* __restrict__ y)
{
    constexpr int CH   = 48;
    constexpr int CICO = CI * CO;
    static_assert(6 * CI <= 256, "phase-A lanes");
    __shared__ float w1s[20];
    __shared__ int   eb[CH], svb[CH];
    __shared__ float hb[CH * 6];
    __shared__ float xs[CH * CI];
    __shared__ float S[6 * CI];

    int t = threadIdx.x;
    int v = blockIdx.x;
    if (t < 20) w1s[t] = (t < 15) ? w1[t] : b1[t - 15];
    int r0 = rp[v], r1 = rp[v + 1];
    int d  = r1 - r0;
    float acc = 0.f;

    for (int c0 = r0; c0 < r1; c0 += CH) {
        int cn = min(CH, r1 - c0);
        if (t < cn) {
            int e = eid[c0 + t];
            eb[t]  = e;
            svb[t] = src[e];
            hb[t * 6] = 1.f;
        }
        __syncthreads();
        if (t < cn * 5) {
            int j = t / 5, k = t % 5;
            int e = eb[j];
            float e0 = eattr[e * 3], e1 = eattr[e * 3 + 1], e2 = eattr[e * 3 + 2];
            hb[j * 6 + 1 + k] =
                tanhf(e0 * w1s[k] + e1 * w1s[5 + k] + e2 * w1s[10 + k] + w1s[15 + k]);
        }
        for (int u = t; u < cn * CI; u += 256)
            xs[u] = x[(size_t)svb[u / CI] * CI + (u % CI)];
        __syncthreads();
        if (t < 6 * CI) {
            int i = t / 6, k6 = t % 6;
            for (int j = 0; j < cn; j++)
                acc += hb[j * 6 + k6] * xs[j * CI + i];
        }
        __syncthreads();
    }

    if (t < 6 * CI) S[t] = acc;
    __syncthreads();

    if (t < CO) {
        float m = 0.f;
        for (int i = 0; i < CI; i++) {
            m += b2[i * CO + t] * S[i * 6];
            #pragma unroll
            for (int k = 0; k < 5; k++)
                m += w2[k * CICO + i * CO + t] * S[i * 6 + 1 + k];
        }
        m /= fmaxf((float)d, 1.f);
        for (int i = 0; i < CI; i++)
            m += x[(size_t)v * CI + i] * root[i * CO + t];
        y[(size_t)v * CO + t] = m + bias[t];
    }
}

// ---------------------------------------------------------------------------
// pool_k (unchanged).
// ---------------------------------------------------------------------------
template<int CO>
__global__ __launch_bounds__(256) void pool_k(
    int NN,
    const int* __restrict__ crp, const int* __restrict__ cnid,
    const float* __restrict__ y, const float* __restrict__ pos,
    float* __restrict__ xn, float* __restrict__ pn)
{
    int t = blockIdx.x * 256 + threadIdx.x;
    if (t >= NN * (CO + 3)) return;
    int c = t / (CO + 3), o = t % (CO + 3);
    int r0 = crp[c], r1 = crp[c + 1];
    int d = r1 - r0;
    if (o < CO) {
        float m = -INFINITY;
        for (int j = r0; j < r1; j++)
            m = fmaxf(m, y[(size_t)cnid[j] * CO + o]);
        if (d == 0 || !isfinite(m)) m = 0.f;
        xn[c * (CO + 3) + o] = m;
    } else {
        int k = o - CO;
        float sum = 0.f;
        for (int j = r0; j < r1; j++)
            sum += pos[cnid[j] * 3 + k];
        float pm = sum / fmaxf((float)d, 1.f);
        xn[c * (CO + 3) + CO + k] = pm;
        pn[c * 3 + k] = pm;
    }
}

// ---------------------------------------------------------------------------
// fc_k (unchanged).
// ---------------------------------------------------------------------------
__global__ __launch_bounds__(128) void fc_k(
    const float* __restrict__ x5,
    const float* __restrict__ fc_w, const float* __restrict__ fc_b,
    const float* __restrict__ sq, float* __restrict__ out)
{
    __shared__ float feat[8 * 376];
    __shared__ float logit[80];
    __shared__ float roff[8];
    for (int t = threadIdx.x; t < 8 * 376; t += 128) feat[t] = x5[t];
    __syncthreads();
    int t = threadIdx.x;
    if (t < 80) {
        int b = t / 10, j = t % 10;
        float acc = fc_b[j];
        for (int k = 0; k < 376; k++) acc += feat[b * 376 + k] * fc_w[k * 10 + j];
        logit[t] = acc;
    }
    __syncthreads();
    if (t < 8) {
        float m = -1e30f;
        for (int j = 0; j < 10; j++) m = fmaxf(m, logit[t * 10 + j]);
        float ssum = 0.f;
        for (int j = 0; j < 10; j++) ssum += expf(logit[t * 10 + j] - m);
        roff[t] = m + logf(ssum);
    }
    __syncthreads();
    if (t < 80) out[t] = logit[t] - roff[t / 10];
    if (t == 0) {
        float closs = 0.f;
        closs += sq[0] * (1.0f / 12582912.0f);
        closs += sq[1] * (1.0f / 78643200.0f);
        closs += sq[2] * (1.0f / 42205184.0f);
        closs += sq[3] * (1.0f / 18284544.0f);
        closs += sq[4] * (1.0f / 7028736.0f);
        out[80] = closs;
    }
}

// ---------------------------------------------------------------------------

extern "C" void kernel_launch(void* const* d_in, const int* in_sizes, int n_in,
                              void* d_out, int out_size, void* d_ws, size_t ws_size,
                              hipStream_t stream)
{
    static const int NSa[6] = {65536, 16384, 4096, 1024, 256, 64};
    static const int ESa[5] = {1048576, 262144, 65536, 16384, 4096};
    static const int COa[5] = {12, 20, 28, 36, 44};
    static const int CIa[5] = {1, 15, 23, 31, 39};

    const float* x0   = (const float*)d_in[0];
    const float* pos0 = (const float*)d_in[1];

    // ---- workspace layout (words), ~42 MB total ----
    int* wsw = (int*)d_ws;
    size_t off = 0;
    auto alw = [&](size_t n) -> size_t {
        size_t p = off; off += (n + 63) & ~(size_t)63; return p;
    };
    size_t degO[5], cdegO[5];
    for (int l = 1; l < 5; l++) degO[l]  = alw(NSa[l]);   // seg0 needs no cnt
    for (int l = 0; l < 5; l++) cdegO[l] = alw(NSa[l + 1]);
    size_t HO = alw(100);
    size_t zeroWords = off;                               // zero-init to here
    size_t rpO[5], crpO[5], eidO[5], cnidO[5];
    rpO[0] = alw(65537);
    for (int l = 1; l < 5; l++) rpO[l]  = alw(NSa[l] + 1);
    for (int l = 0; l < 5; l++) crpO[l] = alw(NSa[l + 1] + 1);
    for (int l = 1; l < 5; l++) eidO[l] = alw(ESa[l]);    // seg0: no eid
    for (int l = 0; l < 5; l++) cnidO[l] = alw(NSa[l]);
    size_t tsO  = alw(64);
    size_t toO  = alw(64);
    size_t MO   = alw((size_t)TILES0 * 128);
    size_t M2O  = alw((size_t)TILES0 * 128);
    size_t ctO  = alw(128);
    size_t bsO  = alw(129);
    size_t keysO = alw((size_t)ESa[0]);
    size_t payO  = alw((size_t)ESa[0] * 4);
    size_t csr0O = alw((size_t)ESa[0] * 4);
    size_t yO  = alw((size_t)65536 * 12);
    size_t sqO = alw(8);
    size_t xnO[5], pnO[5];
    for (int l = 0; l < 5; l++) xnO[l] = alw((size_t)NSa[l + 1] * (COa[l] + 3));
    for (int l = 0; l < 5; l++) pnO[l] = alw((size_t)NSa[l + 1] * 3);

    hipMemsetAsync(d_ws, 0, zeroWords * 4, stream);

    // ---- segs 1-9 descriptor (edge segs 1-4 + cluster segs 0-4) ----
    SegArgs sa{};
    int nseg = 0;
    for (int l = 1; l < 5; l++) {
        sa.idx[nseg] = (const int*)d_in[3 + 10 * l];
        sa.cnt[nseg] = wsw + degO[l];
        sa.rp [nseg] = wsw + rpO[l];
        sa.out[nseg] = wsw + eidO[l];
        sa.n  [nseg] = ESa[l];
        sa.nb [nseg] = NSa[l];
        nseg++;
    }
    for (int l = 0; l < 5; l++) {
        sa.idx[nseg] = (const int*)d_in[5 + 10 * l];
        sa.cnt[nseg] = wsw + cdegO[l];
        sa.rp [nseg] = wsw + crpO[l];
        sa.out[nseg] = wsw + cnidO[l];
        sa.n  [nseg] = NSa[l];
        sa.nb [nseg] = NSa[l + 1];
        nseg++;
    }
    ScanAux sx{};
    int tiles = 0, btiles = 0;
    for (int s = 0; s < nseg; s++) {
        int lg = 31 - __builtin_clz(sa.nb[s]);
        sa.shift[s] = lg - 3;
        sa.tstart[s] = tiles;
        tiles += (sa.n[s] + 255) / 256;
        sx.sstart[s] = btiles;
        btiles += (sa.nb[s] + 4095) / 4096;
    }
    for (int s = nseg; s <= 10; s++) {
        sa.tstart[s] = tiles;
        if (s <= 10) sx.sstart[s > 10 ? 10 : s] = btiles;
        if (s < 10) {
            sa.idx[s] = sa.idx[nseg - 1]; sa.cnt[s] = sa.cnt[nseg - 1];
            sa.rp[s] = sa.rp[nseg - 1];   sa.out[s] = sa.out[nseg - 1];
            sa.n[s] = 0; sa.nb[s] = 8; sa.shift[s] = 0;
        }
    }
    sx.T = btiles;
    sx.tilesum = wsw + tsO;
    sx.tileoff = wsw + toO;

    int*    keys = wsw + keysO;
    float4* pay  = (float4*)(wsw + payO);
    float4* csr0 = (float4*)(wsw + csr0O);
    int*    rp0  = wsw + rpO[0];

    // ---- seg0 deterministic radix build ----
    cnt0_k   <<<TILES0, 256, 0, stream>>>((const int*)d_in[3], wsw + MO);
    colscan_k<<<128, 256, 0, stream>>>(wsw + MO, wsw + M2O, wsw + ctO);
    bktscan_k<<<1, 128, 0, stream>>>(wsw + ctO, wsw + bsO, rp0);
    part0_k  <<<TILES0, 256, 0, stream>>>(
        (const int*)d_in[2], (const int*)d_in[3], (const float*)d_in[4],
        x0, wsw + M2O, wsw + bsO, keys, pay);
    bucket0_k<<<128, 1024, 0, stream>>>(keys, pay, wsw + bsO, rp0, csr0);

    // ---- segs 1-9 atomic build ----
    hist_all_k   <<<tiles * NBUCK, 256, 0, stream>>>(sa);
    scanA_k      <<<btiles, 256, 0, stream>>>(sa, sx);
    scanB_k      <<<1, 64, 0, stream>>>(sa, sx);
    scanC_k      <<<btiles, 256, 0, stream>>>(sa, sx);
    scatter_all_k<<<tiles * NBUCK, 256, 0, stream>>>(sa);

    // ---- closs statistics ----
    HArgs ha{};
    int bs = 0;
    for (int l = 0; l < 5; l++) {
        ha.eattr[l] = (const float*)d_in[4 + 10 * l];
        ha.w1[l]    = (const float*)d_in[6 + 10 * l];
        ha.b1[l]    = (const float*)d_in[7 + 10 * l];
        ha.E[l]     = ESa[l];
        ha.bstart[l] = bs;
        bs += (ESa[l] + 256 * 32 - 1) / (256 * 32);
    }
    ha.bstart[5] = bs;
    ha.H = (float*)(wsw + HO);
    hstats_k<<<bs, 256, 0, stream>>>(ha);

    WArgs wa{};
    for (int l = 0; l < 5; l++) {
        wa.w2[l]   = (const float*)d_in[8 + 10 * l];
        wa.b2[l]   = (const float*)d_in[9 + 10 * l];
        wa.cico[l] = CIa[l] * COa[l];
        wa.E[l]    = ESa[l];
    }
    wa.H  = (const float*)(wsw + HO);
    wa.sq = (float*)(wsw + sqO);
    wstats_k<<<5, 64, 0, stream>>>(wa);

    float* yb = (float*)(wsw + yO);

    // ---- level 0 ----
    conv0_k<<<NSa[0] / 256, 256, 0, stream>>>(
        rp0, csr0,
        (const float*)d_in[6], (const float*)d_in[7],
        (const float*)d_in[8], (const float*)d_in[9],
        (const float*)d_in[10], (const float*)d_in[11], x0, yb);
    pool_k<12><<<(NSa[1] * 15 + 255) / 256, 256, 0, stream>>>(
        NSa[1], wsw + crpO[0], wsw + cnidO[0], yb, pos0,
        (float*)(wsw + xnO[0]), (float*)(wsw + pnO[0]));

    // ---- levels 1-4 ----
#define LVLC(l, CI_, CO_) do {                                                 \
    const float* xin   = (const float*)(wsw + xnO[(l) - 1]);                   \
    const float* posin = (const float*)(wsw + pnO[(l) - 1]);                   \
    int N = NSa[(l)], NN = NSa[(l) + 1];                                       \
    coop_conv_k<CI_, CO_><<<N, 256, 0, stream>>>(                              \
        wsw + rpO[(l)], wsw + eidO[(l)],                                       \
        (const int*)d_in[2 + 10 * (l)], (const float*)d_in[4 + 10 * (l)],      \
        (const float*)d_in[6 + 10 * (l)], (const float*)d_in[7 + 10 * (l)],    \
        (const float*)d_in[8 + 10 * (l)], (const float*)d_in[9 + 10 * (l)],    \
        (const float*)d_in[10 + 10 * (l)], (const float*)d_in[11 + 10 * (l)],  \
        xin, yb);                                                              \
    pool_k<CO_><<<(NN * ((CO_) + 3) + 255) / 256, 256, 0, stream>>>(           \
        NN, wsw + crpO[(l)], wsw + cnidO[(l)], yb, posin,                      \
        (float*)(wsw + xnO[(l)]), (float*)(wsw + pnO[(l)]));                   \
} while (0)

    LVLC(1, 15, 20);
    LVLC(2, 23, 28);
    LVLC(3, 31, 36);
    LVLC(4, 39, 44);
#undef LVLC

    fc_k<<<1, 128, 0, stream>>>((const float*)(wsw + xnO[4]),
                                (const float*)d_in[52], (const float*)d_in[53],
                                (const float*)(wsw + sqO), (float*)d_out);
}